// Round 1
// 260.764 us; speedup vs baseline: 1.1789x; 1.1789x over previous
//
#include <hip/hip_runtime.h>
#include <hip/hip_bf16.h>
#include <math.h>

#define N_NODES  8192
#define N_EDGES  49152
#define E_TOT    57344   // edges + self-loops
#define IN_F     128
#define HID      64
#define NH1      64
#define NH2      5
#define OUT_F    32
#define F1       4096    // NH1*HID
#define F2       160     // NH2*OUT_F
#define N_BONDS  64
#define ET       16      // aggx edge-tile
#define NP       4       // head-group partials for fused gemm12
#define HG       16      // heads per group = NH1/NP

typedef short bf16x8 __attribute__((ext_vector_type(8)));
typedef float f32x4  __attribute__((ext_vector_type(4)));

__device__ __forceinline__ float lrelu(float x){ return x > 0.f ? x : 0.2f*x; }

__device__ __forceinline__ unsigned short bf16_rne(float f){
    unsigned u = __float_as_uint(f);
    unsigned r = u + 0x7FFF + ((u >> 16) & 1);
    return (unsigned short)(r >> 16);
}
__device__ __forceinline__ float bf16f(unsigned short h){
    return __uint_as_float((unsigned)h << 16);
}

// barrier that drains LDS ops but leaves global prefetch loads (vmcnt) in flight
__device__ __forceinline__ void block_sync_lds(){
    asm volatile("s_waitcnt lgkmcnt(0)" ::: "memory");
    __builtin_amdgcn_s_barrier();
    asm volatile("" ::: "memory");
}

// ---------------- CSR build (sort edges by dst) ----------------
__global__ void k_init_counts(int* counts){
    int i = blockIdx.x*256 + threadIdx.x;
    if (i < N_NODES) counts[i] = 1;   // self-loop
}
__global__ void k_count(const int* __restrict__ ei, int* counts){
    int i = blockIdx.x*256 + threadIdx.x;
    if (i < N_EDGES) atomicAdd(&counts[ei[N_EDGES + i]], 1);
}
__global__ __launch_bounds__(1024) void k_scan(const int* __restrict__ counts,
                                               int* __restrict__ row_start,
                                               int* __restrict__ cursor){
    __shared__ int sd[1024];
    int t = threadIdx.x;
    int v[8]; int sum = 0;
    #pragma unroll
    for (int i=0;i<8;i++){ v[i] = counts[t*8+i]; sum += v[i]; }
    sd[t] = sum; __syncthreads();
    for (int off=1; off<1024; off<<=1){
        int vv = (t >= off) ? sd[t-off] : 0;
        __syncthreads();
        sd[t] += vv;
        __syncthreads();
    }
    int run = sd[t] - sum;  // exclusive prefix
    #pragma unroll
    for (int i=0;i<8;i++){ row_start[t*8+i] = run; cursor[t*8+i] = run; run += v[i]; }
    if (t == 1023) row_start[N_NODES] = run;
}
__global__ void k_fill(const int* __restrict__ ei, int* cursor, int* __restrict__ csr_src){
    int i = blockIdx.x*256 + threadIdx.x;
    if (i >= E_TOT) return;
    int s, d;
    if (i < N_EDGES){ s = ei[i]; d = ei[N_EDGES + i]; }
    else { s = i - N_EDGES; d = s; }
    int pos = atomicAdd(&cursor[d], 1);
    csr_src[pos] = s;
}

// ---- pack W1 fp32 -> split-bf16 B-fragment order: [hg][ks][ct][lane][8] ----
__global__ void k_packw1d(const float* __restrict__ W1,
                          unsigned short* __restrict__ fh, unsigned short* __restrict__ fl){
    int g = blockIdx.x*256 + threadIdx.x;            // 64*4*4*64 = 65536 groups
    int lane = g & 63, ct = (g >> 6) & 3, ks = (g >> 8) & 3, hg = g >> 10;
    int col = hg*64 + ct*16 + (lane & 15);
    int k = ks*32 + (lane >> 4)*8;
    const float* src = W1 + (size_t)col*IN_F + k;
    bf16x8 hv, lv;
    #pragma unroll
    for (int j=0;j<8;j++){
        float f = src[j];
        unsigned short hb = bf16_rne(f);
        hv[j] = (short)hb;
        lv[j] = (short)bf16_rne(f - bf16f(hb));
    }
    *(bf16x8*)(fh + (size_t)g*8) = hv;
    *(bf16x8*)(fl + (size_t)g*8) = lv;
}

// ---- pack W2 fp32 -> split-bf16 B-fragment order: [kc][ni][lane][8] ----
__global__ void k_packw2d(const float* __restrict__ W2,
                          unsigned short* __restrict__ fh, unsigned short* __restrict__ fl){
    int g = blockIdx.x*256 + threadIdx.x;            // 128*10*64 = 81920 groups
    int lane = g & 63, ni = (g >> 6) % 10, kc = g / 640;
    int n = ni*16 + (lane & 15);
    int k = kc*32 + (lane >> 4)*8;
    const float* src = W2 + (size_t)n*F1 + k;
    bf16x8 hv, lv;
    #pragma unroll
    for (int j=0;j<8;j++){
        float f = src[j];
        unsigned short hb = bf16_rne(f);
        hv[j] = (short)hb;
        lv[j] = (short)bf16_rne(f - bf16f(hb));
    }
    *(bf16x8*)(fh + (size_t)g*8) = hv;
    *(bf16x8*)(fl + (size_t)g*8) = lv;
}

// ------- attention vectors: vsT[k][h] = sum_c a_s[h,c] * W1[h*64+c, k] -------
__global__ __launch_bounds__(128) void k_attvec(const float* __restrict__ W1,
        const float* __restrict__ a_s, const float* __restrict__ a_d,
        float* __restrict__ vsT, float* __restrict__ vdT){
    int h = blockIdx.x, k = threadIdx.x;
    float s = 0.f, d = 0.f;
    for (int c = 0; c < HID; c++){
        float w = W1[(size_t)(h*HID + c)*IN_F + k];
        s += a_s[h*HID + c] * w;
        d += a_d[h*HID + c] * w;
    }
    vsT[k*NH1 + h] = s;
    vdT[k*NH1 + h] = d;
}

// ---------- alpha dots from x: as1[n,h] = x[n,:] . vsT[:,h] ------------------
__global__ __launch_bounds__(128) void k_alpha1x(const float* __restrict__ x,
        const float* __restrict__ vsT, const float* __restrict__ vdT,
        float* __restrict__ as1, float* __restrict__ ad1){
    int n = blockIdx.x, t = threadIdx.x;
    __shared__ float xs[IN_F];
    xs[t] = x[(size_t)n*IN_F + t];
    __syncthreads();
    if (t < NH1){
        float s = 0.f, d = 0.f;
        for (int k = 0; k < IN_F; k++){
            float xv = xs[k];
            s += xv * vsT[k*NH1 + t];
            d += xv * vdT[k*NH1 + t];
        }
        as1[n*NH1 + t] = s;
        ad1[n*NH1 + t] = d;
    }
}

// ------- x-space aggregation, ALL 64 heads, denom fused, single dispatch -----
// Block per dst node, 256 thr: head-quad hq = t>>4 (4 heads), f0 = (t&15)*8.
// Output: bf16 hi-plane, contiguous 256B runs per (head, node).
__global__ __launch_bounds__(256) void k_aggx64(const float* __restrict__ x,
        const float* __restrict__ as1, const float* __restrict__ ad1,
        const int* __restrict__ row_start, const int* __restrict__ csr_src,
        unsigned short* __restrict__ txhi){
    int n = blockIdx.x, t = threadIdx.x;
    __shared__ float ad_s[NH1];
    __shared__ float wt[ET][NH1];   // 4 KB
    __shared__ int   st[ET];
    __shared__ float xs[ET][IN_F];  // 8 KB
    int e0 = row_start[n], e1 = row_start[n+1];
    if (t < NH1) ad_s[t] = ad1[n*NH1 + t];
    int hq = t >> 4, f0 = (t & 15)*8;
    float acc[4][8] = {};
    float D[4] = {0.f, 0.f, 0.f, 0.f};
    for (int eb = e0; eb < e1; eb += ET){
        int ne = min(ET, e1 - eb);
        if (t < ne) st[t] = csr_src[eb + t];
        __syncthreads();
        for (int idx = t; idx < ne*32; idx += 256){
            int e = idx >> 5, f4 = idx & 31;
            *(float4*)&xs[e][f4*4] = *(const float4*)(x + (size_t)st[e]*IN_F + f4*4);
        }
        for (int idx = t; idx < ne*NH1; idx += 256){
            int e = idx >> 6, hh = idx & 63;
            wt[e][hh] = expf(lrelu(as1[st[e]*NH1 + hh] + ad_s[hh]));
        }
        __syncthreads();
        for (int e = 0; e < ne; e++){
            float4 v0 = *(const float4*)&xs[e][f0];
            float4 v1 = *(const float4*)&xs[e][f0+4];
            float xv[8] = {v0.x,v0.y,v0.z,v0.w,v1.x,v1.y,v1.z,v1.w};
            #pragma unroll
            for (int c=0;c<4;c++){
                float w = wt[e][hq*4 + c];
                D[c] += w;
                #pragma unroll
                for (int j=0;j<8;j++) acc[c][j] += w*xv[j];
            }
        }
        __syncthreads();
    }
    #pragma unroll
    for (int c=0;c<4;c++){
        float dinv = 1.f / D[c];
        bf16x8 hv;
        #pragma unroll
        for (int j=0;j<8;j++) hv[j] = (short)bf16_rne(acc[c][j] * dinv);
        size_t o = ((size_t)(hq*4 + c)*N_NODES + n)*IN_F + f0;
        *(bf16x8*)(txhi + o) = hv;
    }
}

// ------- FUSED layer-1 projection + ELU + layer-2 projection -----------------
// grid (64 row-blocks, NP head-groups); 512 thr = 8 waves (wr = wave>>1 in 0..3
// row-pair, wc = wave&1 col-half). Per block: 128 rows, loop HG=16 heads:
//   stage A=txhi[h] tile (32KB, XOR-swizzled) + W1/W2 frag packs (72KB) in LDS
//   MFMA1 (A x split-W1) -> bias/ELU -> X1 tile (16KB LDS, swizzled)
//   MFMA2 (X1 x split-W2) accumulates 128x160 output across heads in regs.
// Register prefetch pipeline: loads for head h+1 issued at top of iter h,
// ds_written one phase later; raw s_barrier + lgkmcnt-only fences keep the
// global loads in flight across barriers. LDS total 120 KB -> 1 block/CU.
__global__ __launch_bounds__(512, 2) void k_gemm12(
        const unsigned short* __restrict__ txhi,
        const unsigned short* __restrict__ w1fh, const unsigned short* __restrict__ w1fl,
        const unsigned short* __restrict__ w2fh, const unsigned short* __restrict__ w2fl,
        const float* __restrict__ b1,
        float* __restrict__ P){
    __shared__ __attribute__((aligned(16))) unsigned short Als[16384];  // 32 KB A tile (swizzled rows of 128 bf16)
    __shared__ __attribute__((aligned(16))) unsigned short W1s[16384];  // 32 KB [hi|lo][ks4][ct4][lane][8]
    __shared__ __attribute__((aligned(16))) unsigned short W2s[20480];  // 40 KB [hi|lo][ks2][ni10][lane][8]
    __shared__ __attribute__((aligned(16))) unsigned short X1s[8192];   // 16 KB X1 tile (swizzled rows of 64 bf16)

    const int tid  = threadIdx.x;
    const int wave = tid >> 6, lane = tid & 63;
    const int wr = wave >> 1, wc = wave & 1;
    const int q = lane >> 4, l16 = lane & 15;
    const int row0 = blockIdx.x * 128;
    const int g = blockIdx.y;
    const int h0 = g * HG;

    // ---- prologue: load + swizzle-write A[h0]; load W[h0] into pref regs ----
    bf16x8 pa[4], pw1[4], pw2[5];
    {
        const unsigned short* ab = txhi + ((size_t)h0*N_NODES + row0)*IN_F;
        #pragma unroll
        for (int r=0;r<4;r++) pa[r] = *(const bf16x8*)(ab + r*4096 + tid*8);
        #pragma unroll
        for (int r=0;r<2;r++){
            pw1[r]   = *(const bf16x8*)(w1fh + (size_t)h0*8192 + r*4096 + tid*8);
            pw1[2+r] = *(const bf16x8*)(w1fl + (size_t)h0*8192 + r*4096 + tid*8);
        }
        #pragma unroll
        for (int r=0;r<5;r++){
            int so = r*4096 + tid*8;     // so<10240 is wave-uniform (tid<256)
            const unsigned short* s = (so < 10240) ? (w2fh + (size_t)h0*10240 + so)
                                                   : (w2fl + (size_t)h0*10240 + (so - 10240));
            pw2[r] = *(const bf16x8*)s;
        }
        #pragma unroll
        for (int r=0;r<4;r++){
            int so = r*4096 + tid*8;
            int sidx = so ^ (((so >> 7) & 7) << 3);
            *(bf16x8*)&Als[sidx] = pa[r];
        }
    }

    f32x4 acc2[2][5] = {};

    #pragma unroll 1
    for (int hh = 0; hh < HG; hh++){
        const int h = h0 + hh;
        block_sync_lds();                       // B3: A/W ds-writes visible; prev readers done
        // ---- write W[h] from pref regs ----
        #pragma unroll
        for (int r=0;r<4;r++) *(bf16x8*)&W1s[r*4096 + tid*8] = pw1[r];
        #pragma unroll
        for (int r=0;r<5;r++) *(bf16x8*)&W2s[r*4096 + tid*8] = pw2[r];
        // ---- issue prefetch of W[h+1], A[h+1] (stays in flight across barriers) ----
        const int hn = (hh+1 < HG) ? (h+1) : h;
        {
            const unsigned short* ab = txhi + ((size_t)hn*N_NODES + row0)*IN_F;
            #pragma unroll
            for (int r=0;r<4;r++) pa[r] = *(const bf16x8*)(ab + r*4096 + tid*8);
            #pragma unroll
            for (int r=0;r<2;r++){
                pw1[r]   = *(const bf16x8*)(w1fh + (size_t)hn*8192 + r*4096 + tid*8);
                pw1[2+r] = *(const bf16x8*)(w1fl + (size_t)hn*8192 + r*4096 + tid*8);
            }
            #pragma unroll
            for (int r=0;r<5;r++){
                int so = r*4096 + tid*8;
                const unsigned short* s = (so < 10240) ? (w2fh + (size_t)hn*10240 + so)
                                                       : (w2fl + (size_t)hn*10240 + (so - 10240));
                pw2[r] = *(const bf16x8*)s;
            }
        }
        block_sync_lds();                       // B1: W[h] visible
        // ---- MFMA1: X1 = A[h] @ W1[h]^T (split-bf16 B) ----
        bf16x8 af[2][4];
        #pragma unroll
        for (int mi=0;mi<2;mi++){
            int row = (2*wr+mi)*16 + l16;
            #pragma unroll
            for (int ks=0;ks<4;ks++){
                int sidx = (row*128 + ks*32 + q*8) ^ ((row & 7) << 3);
                af[mi][ks] = *(const bf16x8*)&Als[sidx];
            }
        }
        f32x4 c1[2][2] = {};
        #pragma unroll
        for (int ks=0;ks<4;ks++){
            bf16x8 bh[2], bl[2];
            #pragma unroll
            for (int ni=0;ni<2;ni++){
                int f = (ks*4 + 2*wc + ni)*512 + lane*8;
                bh[ni] = *(const bf16x8*)&W1s[f];
                bl[ni] = *(const bf16x8*)&W1s[8192 + f];
            }
            #pragma unroll
            for (int mi=0;mi<2;mi++)
                #pragma unroll
                for (int ni=0;ni<2;ni++){
                    c1[mi][ni] = __builtin_amdgcn_mfma_f32_16x16x32_bf16(af[mi][ks], bh[ni], c1[mi][ni], 0,0,0);
                    c1[mi][ni] = __builtin_amdgcn_mfma_f32_16x16x32_bf16(af[mi][ks], bl[ni], c1[mi][ni], 0,0,0);
                }
        }
        // ---- bias + ELU -> X1s (swizzled bf16) ----
        #pragma unroll
        for (int ni=0;ni<2;ni++){
            int col = (2*wc+ni)*16 + l16;
            float b = b1[h*64 + col];
            #pragma unroll
            for (int mi=0;mi<2;mi++){
                #pragma unroll
                for (int i=0;i<4;i++){
                    float v = c1[mi][ni][i] + b;
                    float o = v > 0.f ? v : expm1f(v);
                    int row = (2*wr+mi)*16 + q*4 + i;
                    int sidx = (row*64 + col) ^ ((row & 7) << 3);
                    X1s[sidx] = bf16_rne(o);
                }
            }
        }
        block_sync_lds();                       // B2: X1 visible; A-region readers done
        // ---- MFMA2: acc2 += X1 @ W2[h-slice]^T (split-bf16 B) ----
        bf16x8 a2[2][2];
        #pragma unroll
        for (int mi=0;mi<2;mi++){
            int row = (2*wr+mi)*16 + l16;
            #pragma unroll
            for (int ks=0;ks<2;ks++){
                int sidx = (row*64 + ks*32 + q*8) ^ ((row & 7) << 3);
                a2[mi][ks] = *(const bf16x8*)&X1s[sidx];
            }
        }
        #pragma unroll
        for (int ks=0;ks<2;ks++){
            bf16x8 bh[5], bl[5];
            #pragma unroll
            for (int ni=0;ni<5;ni++){
                int f = (ks*10 + wc*5 + ni)*512 + lane*8;
                bh[ni] = *(const bf16x8*)&W2s[f];
                bl[ni] = *(const bf16x8*)&W2s[10240 + f];
            }
            #pragma unroll
            for (int mi=0;mi<2;mi++)
                #pragma unroll
                for (int ni=0;ni<5;ni++){
                    acc2[mi][ni] = __builtin_amdgcn_mfma_f32_16x16x32_bf16(a2[mi][ks], bh[ni], acc2[mi][ni], 0,0,0);
                    acc2[mi][ni] = __builtin_amdgcn_mfma_f32_16x16x32_bf16(a2[mi][ks], bl[ni], acc2[mi][ni], 0,0,0);
                }
        }
        // ---- swizzle-write A[h+1] (region free after B2) ----
        #pragma unroll
        for (int r=0;r<4;r++){
            int so = r*4096 + tid*8;
            int sidx = so ^ (((so >> 7) & 7) << 3);
            *(bf16x8*)&Als[sidx] = pa[r];
        }
    }

    // ---- epilogue: head-group partial store ----
    float* outp = P + ((size_t)g*N_NODES + row0)*F2;
    #pragma unroll
    for (int mi=0;mi<2;mi++)
        #pragma unroll
        for (int ni=0;ni<5;ni++)
            #pragma unroll
            for (int i=0;i<4;i++){
                int rr = (2*wr+mi)*16 + q*4 + i;
                int cc = wc*80 + ni*16 + l16;
                outp[(size_t)rr*F2 + cc] = acc2[mi][ni][i];
            }
}

// ---------------- reduce NP head-group partials -> h2 ----------------
__global__ __launch_bounds__(256) void k_reduce(const float* __restrict__ P,
                                                float* __restrict__ h2){
    const int NV = N_NODES*F2/4;
    int i = blockIdx.x*256 + threadIdx.x;
    float4 a = ((const float4*)P)[i];
    #pragma unroll
    for (int kb = 1; kb < NP; kb++){
        float4 b = ((const float4*)P)[(size_t)kb*NV + i];
        a.x += b.x; a.y += b.y; a.z += b.z; a.w += b.w;
    }
    ((float4*)h2)[i] = a;
}

// ---------------- attention dots, layer 2 ----------------
__global__ __launch_bounds__(64) void k_alpha2(const float* __restrict__ h2,
        const float* __restrict__ att_s, const float* __restrict__ att_d,
        float* __restrict__ as2, float* __restrict__ ad2){
    int n = blockIdx.x, t = threadIdx.x;
    float ps = 0.f, pd = 0.f;
    if (t < 40){
        float4 h = *(const float4*)(h2 + (size_t)n*F2 + t*4);
        float4 a = ((const float4*)att_s)[t];
        float4 d = ((const float4*)att_d)[t];
        ps = h.x*a.x + h.y*a.y + h.z*a.z + h.w*a.w;
        pd = h.x*d.x + h.y*d.y + h.z*d.z + h.w*d.w;
    }
    ps += __shfl_xor(ps,1); ps += __shfl_xor(ps,2); ps += __shfl_xor(ps,4);
    pd += __shfl_xor(pd,1); pd += __shfl_xor(pd,2); pd += __shfl_xor(pd,4);
    if (t < 40 && (t & 7) == 0){
        as2[n*NH2 + (t>>3)] = ps;
        ad2[n*NH2 + (t>>3)] = pd;
    }
}

// ------- layer-2 softmax + aggregation + head-mean + b2 ----------------------
__global__ __launch_bounds__(256) void k_agg2(const float* __restrict__ h2,
        const float* __restrict__ as2, const float* __restrict__ ad2,
        const int* __restrict__ row_start, const int* __restrict__ csr_src,
        const float* __restrict__ b2, float* __restrict__ x2){
    int n = blockIdx.x, t = threadIdx.x;
    __shared__ float ad_s[NH2], den_s[NH2], sacc[F2];
    int e0 = row_start[n], e1 = row_start[n+1];
    if (t < NH2) ad_s[t] = ad2[n*NH2 + t];
    __syncthreads();
    if (t < NH2){
        float d = 0.f;
        for (int e=e0;e<e1;e++){
            int s = csr_src[e];
            d += expf(lrelu(as2[s*NH2 + t] + ad_s[t]));
        }
        den_s[t] = d;
    }
    __syncthreads();
    if (t < F2){
        int h = t >> 5;
        float adh  = ad_s[h];
        float dinv = 1.f/den_s[h];
        float acc = 0.f;
        for (int e=e0;e<e1;e++){
            int s = csr_src[e];
            float w = expf(lrelu(as2[s*NH2 + h] + adh)) * dinv;
            acc += w * h2[(size_t)s*F2 + t];
        }
        sacc[t] = acc;
    }
    __syncthreads();
    if (t < OUT_F){
        float v = (sacc[t] + sacc[t+32] + sacc[t+64] + sacc[t+96] + sacc[t+128]) * 0.2f + b2[t];
        x2[n*OUT_F + t] = v;
    }
}

// ---------------- bond scores + softmax over 64 bonds ----------------
__global__ __launch_bounds__(64) void k_bond(const float* __restrict__ x2,
        const int* __restrict__ lefts, const int* __restrict__ rights,
        float* __restrict__ out){
    int b = threadIdx.x;
    int L = lefts[b], R = rights[b];
    float s = 0.f;
    #pragma unroll
    for (int c=0;c<OUT_F;c+=4){
        float4 l4 = *(const float4*)(x2 + (size_t)L*OUT_F + c);
        float4 r4 = *(const float4*)(x2 + (size_t)R*OUT_F + c);
        s += l4.x+l4.y+l4.z+l4.w + r4.x+r4.y+r4.z+r4.w;
    }
    float m = s;
    #pragma unroll
    for (int off=1; off<64; off<<=1) m = fmaxf(m, __shfl_xor(m, off));
    float e = expf(s - m);
    float sum = e;
    #pragma unroll
    for (int off=1; off<64; off<<=1) sum += __shfl_xor(sum, off);
    out[b] = e / sum;
}

extern "C" void kernel_launch(void* const* d_in, const int* in_sizes, int n_in,
                              void* d_out, int out_size, void* d_ws, size_t ws_size,
                              hipStream_t stream){
    const float* x      = (const float*)d_in[0];
    const int*   ei     = (const int*)  d_in[1];
    const int*   lefts  = (const int*)  d_in[2];
    const int*   rights = (const int*)  d_in[3];
    const float* W1     = (const float*)d_in[4];
    const float* att_s1 = (const float*)d_in[5];
    const float* att_d1 = (const float*)d_in[6];
    const float* b1     = (const float*)d_in[7];
    const float* W2     = (const float*)d_in[8];
    const float* att_s2 = (const float*)d_in[9];
    const float* att_d2 = (const float*)d_in[10];
    const float* b2     = (const float*)d_in[11];
    float* out = (float*)d_out;

    // fixed layout (well under ws_size; txhi 134 MB dominates)
    char* ws = (char*)d_ws;
    size_t off = 0;
    auto alloc = [&](size_t bytes) -> void* {
        void* p = ws + off;
        off += (bytes + 255) & ~(size_t)255;
        return p;
    };
    unsigned short* txhi = (unsigned short*)alloc((size_t)NH1*N_NODES*IN_F*2); // 134 MB
    float* part   = (float*)alloc((size_t)NP*N_NODES*F2*4);                    // 21 MB
    float* h2     = (float*)alloc((size_t)N_NODES*F2*4);
    float* as1    = (float*)alloc((size_t)N_NODES*NH1*4);
    float* ad1    = (float*)alloc((size_t)N_NODES*NH1*4);
    float* as2    = (float*)alloc((size_t)N_NODES*NH2*4);
    float* ad2    = (float*)alloc((size_t)N_NODES*NH2*4);
    float* x2     = (float*)alloc((size_t)N_NODES*OUT_F*4);
    float* vsT    = (float*)alloc((size_t)IN_F*NH1*4);
    float* vdT    = (float*)alloc((size_t)IN_F*NH1*4);
    unsigned short* w1fh = (unsigned short*)alloc((size_t)F1*IN_F*2);
    unsigned short* w1fl = (unsigned short*)alloc((size_t)F1*IN_F*2);
    unsigned short* w2fh = (unsigned short*)alloc((size_t)128*10*512*2);
    unsigned short* w2fl = (unsigned short*)alloc((size_t)128*10*512*2);
    int* counts    = (int*)alloc((size_t)N_NODES*4);
    int* row_start = (int*)alloc((size_t)(N_NODES+1)*4);
    int* cursor    = (int*)alloc((size_t)N_NODES*4);
    int* csr_src   = (int*)alloc((size_t)E_TOT*4);

    // CSR by destination
    k_init_counts<<<32, 256, 0, stream>>>(counts);
    k_count<<<192, 256, 0, stream>>>(ei, counts);
    k_scan<<<1, 1024, 0, stream>>>(counts, row_start, cursor);
    k_fill<<<224, 256, 0, stream>>>(ei, cursor, csr_src);

    // fragment-order split-bf16 weight packs (direct from fp32)
    k_packw1d<<<65536/256, 256, 0, stream>>>(W1, w1fh, w1fl);
    k_packw2d<<<81920/256, 256, 0, stream>>>(W2, w2fh, w2fl);

    // alpha dots (once, from x); denominators fused into k_aggx64
    k_attvec<<<NH1, 128, 0, stream>>>(W1, att_s1, att_d1, vsT, vdT);
    k_alpha1x<<<N_NODES, 128, 0, stream>>>(x, vsT, vdT, as1, ad1);

    // layer 1: single-pass aggregation (all heads)
    k_aggx64<<<N_NODES, 256, 0, stream>>>(x, as1, ad1, row_start, csr_src, txhi);

    // FUSED proj1 + ELU + proj2 (head-group partials) + reduce
    k_gemm12<<<dim3(64, NP), 512, 0, stream>>>(txhi, w1fh, w1fl, w2fh, w2fl, b1, part);
    k_reduce<<<N_NODES*F2/4/256, 256, 0, stream>>>(part, h2);

    k_alpha2<<<N_NODES, 64, 0, stream>>>(h2, att_s2, att_d2, as2, ad2);
    k_agg2<<<N_NODES, 256, 0, stream>>>(h2, as2, ad2, row_start, csr_src, b2, x2);

    k_bond<<<1, 64, 0, stream>>>(x2, lefts, rights, out);
}